// Round 4
// baseline (653.764 us; speedup 1.0000x reference)
//
#include <hip/hip_runtime.h>
#include <math.h>
#include <stdint.h>

// Problem: s [B=32, C=64, n=128, m=128] f32; etas [n*m*C = 1048576, 4] f32.
// out [32, 64, 256, 256] f32.
// zeta[r] = argmax_p( gumbel(key42)[r,p] + log(max(eta[r,p],1e-30)) ), r = (i*m+j)*C + c
// out[b,c,2i+px,2j+py] = (zeta[r] == px*2+py) ? s[b,c,i,j] : 0.
//
// PRNG: JAX threefry, jax_threefry_partitionable=True (default since jax 0.4.30):
// element e gets counter u64(e) -> threefry2x32(key, hi32(e)=0, lo32(e)=e) -> o0^o1.

#define NROWS 1048576u            // n*m*C

// threefry2x32-20, key = (0, 42)  (jax.random.key(42))
#define KS0 0u
#define KS1 42u
#define KS2 0x1BD11BF0u           // 0x1BD11BDA ^ 0 ^ 42

__device__ __forceinline__ void threefry2x32(uint32_t x0, uint32_t x1,
                                             uint32_t& o0, uint32_t& o1) {
  x0 += KS0; x1 += KS1;
#define TF_RND(R) { x0 += x1; x1 = (x1 << (R)) | (x1 >> (32 - (R))); x1 ^= x0; }
  TF_RND(13) TF_RND(15) TF_RND(26) TF_RND(6)
  x0 += KS1; x1 += KS2 + 1u;
  TF_RND(17) TF_RND(29) TF_RND(16) TF_RND(24)
  x0 += KS2; x1 += KS0 + 2u;
  TF_RND(13) TF_RND(15) TF_RND(26) TF_RND(6)
  x0 += KS0; x1 += KS1 + 3u;
  TF_RND(17) TF_RND(29) TF_RND(16) TF_RND(24)
  x0 += KS1; x1 += KS2 + 4u;
  TF_RND(13) TF_RND(15) TF_RND(26) TF_RND(6)
  x0 += KS2; x1 += KS0 + 5u;
#undef TF_RND
  o0 = x0; o1 = x1;
}

// JAX uniform(minval=tiny, maxval=1): u = bitcast((bits>>9)|0x3f800000)-1; u==0 -> tiny
__device__ __forceinline__ float bits_to_unit(uint32_t b) {
  float u = __uint_as_float((b >> 9) | 0x3F800000u) - 1.0f;
  return (u == 0.0f) ? 1.17549435e-38f : u;
}

// argmax_p of  -log(-log(u_p)) + log(max(eta_p,1e-30)); each f32 intermediate the
// reference rounds is reproduced as the correctly-rounded-from-double f32 value.
__device__ __forceinline__ int argmax_gumbel(const float* u, const float* eta) {
  float best = -3.4e38f; int bi = 0;
  #pragma unroll
  for (int p = 0; p < 4; ++p) {
    float inner = (float)log((double)u[p]);                 // f32(log u), < 0
    float g     = -(float)log(-(double)inner);              // f32(-log(-log u))
    float logit = (float)log((double)fmaxf(eta[p], 1e-30f));
    float score = g + logit;                                // f32 add
    if (score > best) { best = score; bi = p; }             // ties -> first index
  }
  return bi;
}

// One thread per row r: elements 4r..4r+3, partitionable counter = flat index.
// zc layout: [C=64][n*m=16384] bytes so the scatter kernel reads it coalesced.
__global__ __launch_bounds__(256) void zeta_kernel(const float4* __restrict__ etas,
                                                   uint8_t* __restrict__ zc) {
  const uint32_t t = blockIdx.x * 256u + threadIdx.x;       // row, [0, NROWS)
  float u[4];
  #pragma unroll
  for (int p = 0; p < 4; ++p) {
    uint32_t o0, o1;
    threefry2x32(0u, 4u * t + (uint32_t)p, o0, o1);         // counter hi=0, lo=4r+p
    u[p] = bits_to_unit(o0 ^ o1);                           // partitionable 64->32 fold
  }
  const float4 e4 = etas[t];                                // coalesced
  const float eta[4] = {e4.x, e4.y, e4.z, e4.w};
  const int z = argmax_gumbel(u, eta);
  // row r -> c = r & 63, pos = r >> 6  (r = (i*m+j)*C + c)
  zc[(t & 63u) * 16384u + (t >> 6)] = (uint8_t)z;
}

// One thread per output float4 (y = 4*yq .. 4*yq+3): 2 source pixels x 2 py slots.
__global__ __launch_bounds__(256) void scatter_kernel(const float* __restrict__ s,
                                                      const uint8_t* __restrict__ zc,
                                                      float4* __restrict__ out) {
  const uint32_t t  = blockIdx.x * 256u + threadIdx.x;      // [0, 33554432)
  const uint32_t yq = t & 63u;                              // y / 4
  const uint32_t x  = (t >> 6) & 255u;                      // output row
  const uint32_t bc = t >> 14;                              // b*64 + c
  const uint32_t c  = bc & 63u;
  const uint32_t i  = x >> 1, px = x & 1u;
  const uint32_t j0 = yq << 1;                              // first source col
  const float2 s2 = *reinterpret_cast<const float2*>(
      &s[((size_t)bc << 14) + (i << 7) + j0]);              // s[b,c,i,j0..j0+1]
  const uint32_t zidx = c * 16384u + (i << 7) + j0;
  const uint8_t z0 = zc[zidx], z1 = zc[zidx + 1u];
  const uint32_t p0 = px << 1, p1 = p0 + 1u;
  float4 o;
  o.x = (z0 == (uint8_t)p0) ? s2.x : 0.0f;                  // (j0,   py=0)
  o.y = (z0 == (uint8_t)p1) ? s2.x : 0.0f;                  // (j0,   py=1)
  o.z = (z1 == (uint8_t)p0) ? s2.y : 0.0f;                  // (j0+1, py=0)
  o.w = (z1 == (uint8_t)p1) ? s2.y : 0.0f;                  // (j0+1, py=1)
  out[t] = o;
}

extern "C" void kernel_launch(void* const* d_in, const int* in_sizes, int n_in,
                              void* d_out, int out_size, void* d_ws, size_t ws_size,
                              hipStream_t stream) {
  const float*  s    = (const float*)d_in[0];               // 33554432 f32
  const float4* etas = (const float4*)d_in[1];              // 1048576 float4
  float4*  out = (float4*)d_out;                            // 33554432 float4
  uint8_t* zc  = (uint8_t*)d_ws;                            // 1 MiB scratch

  zeta_kernel<<<NROWS / 256u, 256, 0, stream>>>(etas, zc);
  scatter_kernel<<<33554432u / 256u, 256, 0, stream>>>(s, zc, out);
}

// Round 5
// 631.764 us; speedup vs baseline: 1.0348x; 1.0348x over previous
//
#include <hip/hip_runtime.h>
#include <math.h>
#include <stdint.h>

// Problem: s [B=32, C=64, n=128, m=128] f32; etas [n*m*C = 1048576, 4] f32.
// out [32, 64, 256, 256] f32.
// zeta[r] = argmax_p( gumbel(key42)[r,p] + log(max(eta[r,p],1e-30)) ), r = (i*m+j)*C + c
// out[b,c,2i+px,2j+py] = (zeta[r] == px*2+py) ? s[b,c,i,j] : 0.
//
// PRNG: JAX threefry, jax_threefry_partitionable=True (default since jax 0.4.30):
// element e -> threefry2x32(key, hi32(e)=0, lo32(e)=e) -> fold o0^o1.  (verified R4: absmax=0)

#define NROWS 1048576u            // n*m*C

// threefry2x32-20, key = (0, 42)  (jax.random.key(42))
#define KS0 0u
#define KS1 42u
#define KS2 0x1BD11BF0u           // 0x1BD11BDA ^ 0 ^ 42

typedef float f32x4 __attribute__((ext_vector_type(4)));

__device__ __forceinline__ void threefry2x32(uint32_t x0, uint32_t x1,
                                             uint32_t& o0, uint32_t& o1) {
  x0 += KS0; x1 += KS1;
#define TF_RND(R) { x0 += x1; x1 = (x1 << (R)) | (x1 >> (32 - (R))); x1 ^= x0; }
  TF_RND(13) TF_RND(15) TF_RND(26) TF_RND(6)
  x0 += KS1; x1 += KS2 + 1u;
  TF_RND(17) TF_RND(29) TF_RND(16) TF_RND(24)
  x0 += KS2; x1 += KS0 + 2u;
  TF_RND(13) TF_RND(15) TF_RND(26) TF_RND(6)
  x0 += KS0; x1 += KS1 + 3u;
  TF_RND(17) TF_RND(29) TF_RND(16) TF_RND(24)
  x0 += KS1; x1 += KS2 + 4u;
  TF_RND(13) TF_RND(15) TF_RND(26) TF_RND(6)
  x0 += KS2; x1 += KS0 + 5u;
#undef TF_RND
  o0 = x0; o1 = x1;
}

// JAX uniform(minval=tiny, maxval=1): u = bitcast((bits>>9)|0x3f800000)-1; u==0 -> tiny
__device__ __forceinline__ float bits_to_unit(uint32_t b) {
  float u = __uint_as_float((b >> 9) | 0x3F800000u) - 1.0f;
  return (u == 0.0f) ? 1.17549435e-38f : u;
}

// f32(log(x)) for normal positive x, branch-light inline f64 log.
// rel err < 1e-13 -> f32 rounding differs from correctly-rounded in ~1.7e-6 of calls
// (1 ulp), statistically invisible to the argmax (needs a sub-ulp top-2 tie as well).
__device__ __forceinline__ float log_cr(double x) {
  const int64_t ib = (int64_t)__double_as_longlong(x);
  int e = (int)((ib >> 52) & 0x7FF) - 1023;
  double r = __longlong_as_double((ib & 0xFFFFFFFFFFFFFLL) | 0x3FF0000000000000LL);
  if (r > 1.4142135623730951) { r *= 0.5; e += 1; }        // r in [sqrt2/2, sqrt2)
  const double s  = (r - 1.0) / (r + 1.0);                 // |s| <= 0.1716
  const double s2 = s * s;                                 // <= 0.02944
  double p = fma(s2, 1.0/15.0, 1.0/13.0);                  // atanh tail, trunc err ~3e-14
  p = fma(s2, p, 1.0/11.0);
  p = fma(s2, p, 1.0/9.0);
  p = fma(s2, p, 1.0/7.0);
  p = fma(s2, p, 1.0/5.0);
  p = fma(s2, p, 1.0/3.0);
  const double logr = 2.0 * fma(s * s2, p, s);             // log(r) = 2*atanh(s)
  return (float)fma((double)e, 0.6931471805599453, logr);
}

// argmax_p of  -log(-log(u_p)) + log(max(eta_p,1e-30)); every f32 intermediate the
// reference rounds is reproduced (to within the 1e-13 log note above).
__device__ __forceinline__ int argmax_gumbel(const float* u, const float* eta) {
  float best = -3.4e38f; int bi = 0;
  #pragma unroll
  for (int p = 0; p < 4; ++p) {
    float inner = log_cr((double)u[p]);                    // f32(log u), < 0
    float g     = -log_cr(-(double)inner);                 // f32(-log(-log u))
    float logit = log_cr((double)fmaxf(eta[p], 1e-30f));
    float score = g + logit;                               // f32 add
    if (score > best) { best = score; bi = p; }            // ties -> first index
  }
  return bi;
}

// One thread per row r: elements 4r..4r+3, partitionable counter = flat index.
// zc layout: [C=64][n*m=16384] bytes so the scatter kernel reads it coalesced.
// (zc is 1 MiB: the 64-lane byte-scatter write is absorbed by L2, cost hidden.)
__global__ __launch_bounds__(256) void zeta_kernel(const float4* __restrict__ etas,
                                                   uint8_t* __restrict__ zc) {
  const uint32_t t = blockIdx.x * 256u + threadIdx.x;      // row, [0, NROWS)
  float u[4];
  #pragma unroll
  for (int p = 0; p < 4; ++p) {
    uint32_t o0, o1;
    threefry2x32(0u, 4u * t + (uint32_t)p, o0, o1);        // counter hi=0, lo=4r+p
    u[p] = bits_to_unit(o0 ^ o1);                          // partitionable 64->32 fold
  }
  const float4 e4 = etas[t];                               // coalesced
  const float eta[4] = {e4.x, e4.y, e4.z, e4.w};
  const int z = argmax_gumbel(u, eta);
  zc[(t & 63u) * 16384u + (t >> 6)] = (uint8_t)z;          // c = r&63, pos = r>>6
}

// One thread per (bc, i, yq): shares the s/zc loads across both output rows
// x = 2i (px=0) and x = 2i+1 (px=1); two nontemporal float4 stores (streamed, no reuse).
__global__ __launch_bounds__(256) void scatter_kernel(const float* __restrict__ s,
                                                      const uint8_t* __restrict__ zc,
                                                      f32x4* __restrict__ out) {
  const uint32_t t  = blockIdx.x * 256u + threadIdx.x;     // [0, 16777216)
  const uint32_t yq = t & 63u;                             // y / 4
  const uint32_t i  = (t >> 6) & 127u;                     // source row
  const uint32_t bc = t >> 13;                             // b*64 + c
  const uint32_t c  = bc & 63u;
  const uint32_t j0 = yq << 1;                             // first source col
  const float2 s2 = *reinterpret_cast<const float2*>(
      &s[((size_t)bc << 14) + (i << 7) + j0]);             // s[b,c,i,j0..j0+1]
  const uint32_t zidx = c * 16384u + (i << 7) + j0;
  const uint8_t z0 = zc[zidx], z1 = zc[zidx + 1u];
  f32x4 o0, o1;
  o0.x = (z0 == 0) ? s2.x : 0.0f;                          // (2i,   2j0,   )
  o0.y = (z0 == 1) ? s2.x : 0.0f;                          // (2i,   2j0+1 )
  o0.z = (z1 == 0) ? s2.y : 0.0f;
  o0.w = (z1 == 1) ? s2.y : 0.0f;
  o1.x = (z0 == 2) ? s2.x : 0.0f;                          // (2i+1, 2j0   )
  o1.y = (z0 == 3) ? s2.x : 0.0f;
  o1.z = (z1 == 2) ? s2.y : 0.0f;
  o1.w = (z1 == 3) ? s2.y : 0.0f;
  const uint32_t ob = (bc << 14) | (i << 7) | yq;          // float4 index, row x=2i
  __builtin_nontemporal_store(o0, &out[ob]);
  __builtin_nontemporal_store(o1, &out[ob + 64u]);         // row x=2i+1
}

extern "C" void kernel_launch(void* const* d_in, const int* in_sizes, int n_in,
                              void* d_out, int out_size, void* d_ws, size_t ws_size,
                              hipStream_t stream) {
  const float*  s    = (const float*)d_in[0];              // 33554432 f32
  const float4* etas = (const float4*)d_in[1];             // 1048576 float4
  f32x4*   out = (f32x4*)d_out;                            // 33554432 float4
  uint8_t* zc  = (uint8_t*)d_ws;                           // 1 MiB scratch

  zeta_kernel<<<NROWS / 256u, 256, 0, stream>>>(etas, zc);
  scatter_kernel<<<16777216u / 256u, 256, 0, stream>>>(s, zc, out);
}

// Round 7
// 629.133 us; speedup vs baseline: 1.0392x; 1.0042x over previous
//
#include <hip/hip_runtime.h>
#include <math.h>
#include <stdint.h>

// Problem: s [B=32, C=64, n=128, m=128] f32; etas [n*m*C = 1048576, 4] f32.
// out [32, 64, 256, 256] f32.
// zeta[r] = argmax_p( gumbel(key42)[r,p] + log(max(eta[r,p],1e-30)) ), r = (i*m+j)*C + c
// out[b,c,2i+px,2j+py] = (zeta[r] == px*2+py) ? s[b,c,i,j] : 0.
//
// PRNG: JAX threefry, jax_threefry_partitionable=True (default since jax 0.4.30):
// element e -> threefry2x32(key, hi32(e)=0, lo32(e)=e) -> fold o0^o1.
// This exact source passed end-to-end in R5 (absmax=0, all tripwires).

#define NROWS 1048576u            // n*m*C

// threefry2x32-20, key = (0, 42)  (jax.random.key(42))
#define KS0 0u
#define KS1 42u
#define KS2 0x1BD11BF0u           // 0x1BD11BDA ^ 0 ^ 42

typedef float f32x4 __attribute__((ext_vector_type(4)));

__device__ __forceinline__ void threefry2x32(uint32_t x0, uint32_t x1,
                                             uint32_t& o0, uint32_t& o1) {
  x0 += KS0; x1 += KS1;
#define TF_RND(R) { x0 += x1; x1 = (x1 << (R)) | (x1 >> (32 - (R))); x1 ^= x0; }
  TF_RND(13) TF_RND(15) TF_RND(26) TF_RND(6)
  x0 += KS1; x1 += KS2 + 1u;
  TF_RND(17) TF_RND(29) TF_RND(16) TF_RND(24)
  x0 += KS2; x1 += KS0 + 2u;
  TF_RND(13) TF_RND(15) TF_RND(26) TF_RND(6)
  x0 += KS0; x1 += KS1 + 3u;
  TF_RND(17) TF_RND(29) TF_RND(16) TF_RND(24)
  x0 += KS1; x1 += KS2 + 4u;
  TF_RND(13) TF_RND(15) TF_RND(26) TF_RND(6)
  x0 += KS2; x1 += KS0 + 5u;
#undef TF_RND
  o0 = x0; o1 = x1;
}

// JAX uniform(minval=tiny, maxval=1): u = bitcast((bits>>9)|0x3f800000)-1; u==0 -> tiny
__device__ __forceinline__ float bits_to_unit(uint32_t b) {
  float u = __uint_as_float((b >> 9) | 0x3F800000u) - 1.0f;
  return (u == 0.0f) ? 1.17549435e-38f : u;
}

// f32(log(x)) for normal positive x, branch-light inline f64 log.
// rel err < 1e-13 -> f32 rounding differs from correctly-rounded in ~1.7e-6 of calls
// (1 ulp each), statistically invisible to the argmax (verified R5: absmax=0).
__device__ __forceinline__ float log_cr(double x) {
  const int64_t ib = (int64_t)__double_as_longlong(x);
  int e = (int)((ib >> 52) & 0x7FF) - 1023;
  double r = __longlong_as_double((ib & 0xFFFFFFFFFFFFFLL) | 0x3FF0000000000000LL);
  if (r > 1.4142135623730951) { r *= 0.5; e += 1; }        // r in [sqrt2/2, sqrt2)
  const double s  = (r - 1.0) / (r + 1.0);                 // |s| <= 0.1716
  const double s2 = s * s;                                 // <= 0.02944
  double p = fma(s2, 1.0/15.0, 1.0/13.0);                  // atanh tail, trunc err ~3e-14
  p = fma(s2, p, 1.0/11.0);
  p = fma(s2, p, 1.0/9.0);
  p = fma(s2, p, 1.0/7.0);
  p = fma(s2, p, 1.0/5.0);
  p = fma(s2, p, 1.0/3.0);
  const double logr = 2.0 * fma(s * s2, p, s);             // log(r) = 2*atanh(s)
  return (float)fma((double)e, 0.6931471805599453, logr);
}

// argmax_p of  -log(-log(u_p)) + log(max(eta_p,1e-30)); every f32 intermediate the
// reference rounds is reproduced (to within the 1e-13 log note above).
__device__ __forceinline__ int argmax_gumbel(const float* u, const float* eta) {
  float best = -3.4e38f; int bi = 0;
  #pragma unroll
  for (int p = 0; p < 4; ++p) {
    float inner = log_cr((double)u[p]);                    // f32(log u), < 0
    float g     = -log_cr(-(double)inner);                 // f32(-log(-log u))
    float logit = log_cr((double)fmaxf(eta[p], 1e-30f));
    float score = g + logit;                               // f32 add
    if (score > best) { best = score; bi = p; }            // ties -> first index
  }
  return bi;
}

// One thread per row r: elements 4r..4r+3, partitionable counter = flat index.
// zc layout: [C=64][n*m=16384] bytes so the scatter kernel reads it coalesced.
// (zc is 1 MiB: the 64-lane byte-scatter write is absorbed by L2, ~3 us.)
__global__ __launch_bounds__(256) void zeta_kernel(const float4* __restrict__ etas,
                                                   uint8_t* __restrict__ zc) {
  const uint32_t t = blockIdx.x * 256u + threadIdx.x;      // row, [0, NROWS)
  float u[4];
  #pragma unroll
  for (int p = 0; p < 4; ++p) {
    uint32_t o0, o1;
    threefry2x32(0u, 4u * t + (uint32_t)p, o0, o1);        // counter hi=0, lo=4r+p
    u[p] = bits_to_unit(o0 ^ o1);                          // partitionable 64->32 fold
  }
  const float4 e4 = etas[t];                               // coalesced
  const float eta[4] = {e4.x, e4.y, e4.z, e4.w};
  const int z = argmax_gumbel(u, eta);
  zc[(t & 63u) * 16384u + (t >> 6)] = (uint8_t)z;          // c = r&63, pos = r>>6
}

// One thread per (bc, i, yq): shares the s/zc loads across both output rows
// x = 2i (px=0) and x = 2i+1 (px=1); two nontemporal float4 stores (streamed, no reuse).
__global__ __launch_bounds__(256) void scatter_kernel(const float* __restrict__ s,
                                                      const uint8_t* __restrict__ zc,
                                                      f32x4* __restrict__ out) {
  const uint32_t t  = blockIdx.x * 256u + threadIdx.x;     // [0, 16777216)
  const uint32_t yq = t & 63u;                             // y / 4
  const uint32_t i  = (t >> 6) & 127u;                     // source row
  const uint32_t bc = t >> 13;                             // b*64 + c
  const uint32_t c  = bc & 63u;
  const uint32_t j0 = yq << 1;                             // first source col
  const float2 s2 = *reinterpret_cast<const float2*>(
      &s[((size_t)bc << 14) + (i << 7) + j0]);             // s[b,c,i,j0..j0+1]
  const uint32_t zidx = c * 16384u + (i << 7) + j0;
  const uint8_t z0 = zc[zidx], z1 = zc[zidx + 1u];
  f32x4 o0, o1;
  o0.x = (z0 == 0) ? s2.x : 0.0f;                          // (2i,   2j0   )
  o0.y = (z0 == 1) ? s2.x : 0.0f;                          // (2i,   2j0+1 )
  o0.z = (z1 == 0) ? s2.y : 0.0f;
  o0.w = (z1 == 1) ? s2.y : 0.0f;
  o1.x = (z0 == 2) ? s2.x : 0.0f;                          // (2i+1, 2j0   )
  o1.y = (z0 == 3) ? s2.x : 0.0f;
  o1.z = (z1 == 2) ? s2.y : 0.0f;
  o1.w = (z1 == 3) ? s2.y : 0.0f;
  const uint32_t ob = (bc << 14) | (i << 7) | yq;          // float4 index, row x=2i
  __builtin_nontemporal_store(o0, &out[ob]);
  __builtin_nontemporal_store(o1, &out[ob + 64u]);         // row x=2i+1
}

extern "C" void kernel_launch(void* const* d_in, const int* in_sizes, int n_in,
                              void* d_out, int out_size, void* d_ws, size_t ws_size,
                              hipStream_t stream) {
  const float*  s    = (const float*)d_in[0];              // 33554432 f32
  const float4* etas = (const float4*)d_in[1];             // 1048576 float4
  f32x4*   out = (f32x4*)d_out;                            // 33554432 float4
  uint8_t* zc  = (uint8_t*)d_ws;                           // 1 MiB scratch

  zeta_kernel<<<NROWS / 256u, 256, 0, stream>>>(etas, zc);
  scatter_kernel<<<16777216u / 256u, 256, 0, stream>>>(s, zc, out);
}